// Round 9
// baseline (146.016 us; speedup 1.0000x reference)
//
#include <hip/hip_runtime.h>
#include <hip/hip_bf16.h>

// DigitCaps, fp32 in / fp32 out:
//   u [16,1152,8], W [10,1152,16,8], Bp [10,1,1152], out [16,10,16]
// Exact algebra: A_sum[b,d,m] = dot(T[b,d,:], U_hat[b,d,m,:])/sqrt8,
//   T = sum_n U_hat;  C = softmax_d;  S = sum_n (Bp+C)*U_hat;  squash(S).
// Round-8 lesson: 2.2M fp32 atomicAdds onto 20 KB (576 serialized RMW/cell)
// dominated. Now: atomic-free partial buffers + tree reduction; memset gone.
constexpr int BN = 16, NN = 1152, DP = 8, ND = 10, DD = 16;
constexpr int NCHA = 4;                  // n's per caps_T block
constexpr int NBLK_A = NN / NCHA;        // 288
constexpr int NCHB = 2;                  // n's per caps_S block
constexpr int NBLK_B = NN / NCHB;        // 576
constexpr int CELLS = BN * ND * DD;      // 2560; cell = d*256 + b*16 + j

__device__ __forceinline__ void load8(const float* __restrict__ p, float* dst) {
    const float4 a = reinterpret_cast<const float4*>(p)[0];
    const float4 b = reinterpret_cast<const float4*>(p)[1];
    dst[0] = a.x; dst[1] = a.y; dst[2] = a.z; dst[3] = a.w;
    dst[4] = b.x; dst[5] = b.y; dst[6] = b.z; dst[7] = b.w;
}

// ---- Phase A: per-block partial T; thread=(b,j), 10 reg accumulators ----
__global__ __launch_bounds__(256) void caps_T(
    const float* __restrict__ u, const float* __restrict__ W,
    float* __restrict__ Tp)
{
    const int t = threadIdx.x, j = t & 15, b = t >> 4;
    const int n0 = blockIdx.x * NCHA;
    float Tacc[ND];
#pragma unroll
    for (int d = 0; d < ND; ++d) Tacc[d] = 0.f;

    for (int nn = 0; nn < NCHA; ++nn) {
        const int n = n0 + nn;
        float uf[DP];
        load8(u + ((size_t)b * NN + n) * DP, uf);
#pragma unroll
        for (int d = 0; d < ND; ++d) {          // 10 independent load8s
            float wf[DP];
            load8(W + (((size_t)d * NN + n) * DD + j) * DP, wf);
            float s = 0.f;
#pragma unroll
            for (int i = 0; i < DP; ++i) s += wf[i] * uf[i];
            Tacc[d] += s;
        }
    }
    float* dst = Tp + (size_t)blockIdx.x * CELLS;
#pragma unroll
    for (int d = 0; d < ND; ++d) dst[d * 256 + t] = Tacc[d];  // 1KB runs
}

// ---- reduce Tp[288][2560] -> T[2560]; coalesced stride-2560 loads ----
__global__ __launch_bounds__(256) void reduce_T(
    const float* __restrict__ Tp, float* __restrict__ T)
{
    const int cell = blockIdx.x * 256 + threadIdx.x;
    float s0 = 0.f, s1 = 0.f, s2 = 0.f, s3 = 0.f;
    for (int c = 0; c < NBLK_A; c += 4) {
        s0 += Tp[(size_t)(c + 0) * CELLS + cell];
        s1 += Tp[(size_t)(c + 1) * CELLS + cell];
        s2 += Tp[(size_t)(c + 2) * CELLS + cell];
        s3 += Tp[(size_t)(c + 3) * CELLS + cell];
    }
    T[cell] = (s0 + s1) + (s2 + s3);
}

// ---- Phase B: scores -> softmax_d -> partial S; no atomics ----
__global__ __launch_bounds__(256) void caps_S(
    const float* __restrict__ u, const float* __restrict__ W,
    const float* __restrict__ Bp, const float* __restrict__ T,
    float* __restrict__ Sp)
{
    const int t = threadIdx.x, j = t & 15, b = t >> 4;
    constexpr float RS8 = 0.35355339059327373f;  // 1/sqrt(8)

    float Treg[ND];                               // T[.,b,j] (L2-hot 10 KB)
#pragma unroll
    for (int q = 0; q < ND; ++q) Treg[q] = T[q * 256 + t];

    float Sacc[ND];
#pragma unroll
    for (int q = 0; q < ND; ++q) Sacc[q] = 0.f;

    const int n0 = blockIdx.x * NCHB;
    for (int nn = 0; nn < NCHB; ++nn) {
        const int n = n0 + nn;
        float uf[DP];
        load8(u + ((size_t)b * NN + n) * DP, uf);

        float uh[ND], a[ND];
#pragma unroll
        for (int q = 0; q < ND; ++q) {            // 10 independent load8s
            float wf[DP];
            load8(W + (((size_t)q * NN + n) * DD + j) * DP, wf);
            float s = 0.f;
#pragma unroll
            for (int i = 0; i < DP; ++i) s += wf[i] * uf[i];
            uh[q] = s;
            float v = Treg[q] * s;                // butterfly over 16 j-lanes
            v += __shfl_xor(v, 8, 16);
            v += __shfl_xor(v, 4, 16);
            v += __shfl_xor(v, 2, 16);
            v += __shfl_xor(v, 1, 16);
            a[q] = v * RS8;
        }
        float m = a[0];
#pragma unroll
        for (int q = 1; q < ND; ++q) m = fmaxf(m, a[q]);
        float e[ND], se = 0.f;
#pragma unroll
        for (int q = 0; q < ND; ++q) { e[q] = expf(a[q] - m); se += e[q]; }
        const float inv_se = 1.f / se;
#pragma unroll
        for (int q = 0; q < ND; ++q)
            Sacc[q] += (Bp[q * NN + n] + e[q] * inv_se) * uh[q];
    }
    float* dst = Sp + (size_t)blockIdx.x * CELLS;
#pragma unroll
    for (int q = 0; q < ND; ++q) dst[q * 256 + t] = Sacc[q];
}

// ---- reduce Sp[576][2560] + fused squash + store ----
__global__ __launch_bounds__(256) void reduce_S_out(
    const float* __restrict__ Sp, float* __restrict__ out)
{
    const int q = blockIdx.x, t = threadIdx.x;    // t = b*16 + j
    const int cell = q * 256 + t;
    float s0 = 0.f, s1 = 0.f, s2 = 0.f, s3 = 0.f;
    for (int c = 0; c < NBLK_B; c += 4) {
        s0 += Sp[(size_t)(c + 0) * CELLS + cell];
        s1 += Sp[(size_t)(c + 1) * CELLS + cell];
        s2 += Sp[(size_t)(c + 2) * CELLS + cell];
        s3 += Sp[(size_t)(c + 3) * CELLS + cell];
    }
    const float Sv = (s0 + s1) + (s2 + s3);
    float n2 = Sv * Sv;                           // 16-lane aligned groups
#pragma unroll
    for (int off = 8; off >= 1; off >>= 1) n2 += __shfl_xor(n2, off, 16);
    const float nrm = sqrtf(n2);
    const float coef = 1.f - 1.f / (expf(nrm) + 1e-7f);
    const int b = t >> 4, j = t & 15;
    out[((size_t)b * ND + q) * DD + j] = Sv * (coef / (nrm + 1e-7f));
}

extern "C" void kernel_launch(void* const* d_in, const int* in_sizes, int n_in,
                              void* d_out, int out_size, void* d_ws, size_t ws_size,
                              hipStream_t stream) {
    const float* u  = nullptr;   // 147456
    const float* W  = nullptr;   // 1474560
    const float* Bp = nullptr;   // 11520
    for (int i = 0; i < n_in; ++i) {
        const int s = in_sizes[i];
        if (s == BN * NN * DP)            u  = (const float*)d_in[i];
        else if (s == ND * NN * DD * DP)  W  = (const float*)d_in[i];
        else if (s == ND * NN)            Bp = (const float*)d_in[i];
    }
    float* out = (float*)d_out;
    float* Tp = (float*)d_ws;                     // 288*2560 fp32 = 2.95 MB
    float* T  = Tp + (size_t)NBLK_A * CELLS;      // 2560 fp32
    float* Sp = T + CELLS;                        // 576*2560 fp32 = 5.9 MB

    caps_T      <<<dim3(NBLK_A), 256, 0, stream>>>(u, W, Tp);
    reduce_T    <<<dim3(CELLS / 256), 256, 0, stream>>>(Tp, T);
    caps_S      <<<dim3(NBLK_B), 256, 0, stream>>>(u, W, Bp, T, Sp);
    reduce_S_out<<<dim3(ND), 256, 0, stream>>>(Sp, out);
}

// Round 10
// 84.824 us; speedup vs baseline: 1.7214x; 1.7214x over previous
//
#include <hip/hip_runtime.h>
#include <hip/hip_bf16.h>

// DigitCaps, fp32 in / fp32 out:
//   u [16,1152,8], W [10,1152,16,8], Bp [10,1,1152], out [16,10,16]
// Exact algebra: A_sum[b,d,m] = dot(T[b,d,:], U_hat[b,d,m,:])/sqrt8,
//   T = sum_n U_hat;  C = softmax_d;  S = sum_n (Bp+C)*U_hat;  squash(S).
// Round-9 lesson: the 10-block reduce kernels were latency-bound disasters
// (reduce_S_out 45.6 us, occ 0.39%, 144 chained load-groups). Round 10:
// reductions get 160 blocks with 16 lanes/cell (36 chained loads) + LDS fold;
// caps_T doubled to 576 blocks. Atomic-free and deterministic throughout.
constexpr int BN = 16, NN = 1152, DP = 8, ND = 10, DD = 16;
constexpr int NCHA = 2;                  // n's per caps_T block
constexpr int NBLK_A = NN / NCHA;        // 576
constexpr int NCHB = 2;                  // n's per caps_S block
constexpr int NBLK_B = NN / NCHB;        // 576
constexpr int CELLS = BN * ND * DD;      // 2560; cell = d*256 + b*16 + j
constexpr int RL = 16;                   // reduction lanes per cell

__device__ __forceinline__ void load8(const float* __restrict__ p, float* dst) {
    const float4 a = reinterpret_cast<const float4*>(p)[0];
    const float4 b = reinterpret_cast<const float4*>(p)[1];
    dst[0] = a.x; dst[1] = a.y; dst[2] = a.z; dst[3] = a.w;
    dst[4] = b.x; dst[5] = b.y; dst[6] = b.z; dst[7] = b.w;
}

// ---- Phase A: per-block partial T; thread=(b,j), 10 reg accumulators ----
__global__ __launch_bounds__(256) void caps_T(
    const float* __restrict__ u, const float* __restrict__ W,
    float* __restrict__ Tp)
{
    const int t = threadIdx.x, j = t & 15, b = t >> 4;
    const int n0 = blockIdx.x * NCHA;
    float Tacc[ND];
#pragma unroll
    for (int d = 0; d < ND; ++d) Tacc[d] = 0.f;

    for (int nn = 0; nn < NCHA; ++nn) {
        const int n = n0 + nn;
        float uf[DP];
        load8(u + ((size_t)b * NN + n) * DP, uf);
#pragma unroll
        for (int d = 0; d < ND; ++d) {          // 10 independent load8s
            float wf[DP];
            load8(W + (((size_t)d * NN + n) * DD + j) * DP, wf);
            float s = 0.f;
#pragma unroll
            for (int i = 0; i < DP; ++i) s += wf[i] * uf[i];
            Tacc[d] += s;
        }
    }
    float* dst = Tp + (size_t)blockIdx.x * CELLS;
#pragma unroll
    for (int d = 0; d < ND; ++d) dst[d * 256 + t] = Tacc[d];  // 1KB runs
}

// ---- reduce Tp[576][2560] -> T[2560]: 160 blocks, 16 lanes/cell ----
__global__ __launch_bounds__(256) void reduce_T(
    const float* __restrict__ Tp, float* __restrict__ T)
{
    __shared__ float red[256];
    const int t = threadIdx.x;
    const int cell = blockIdx.x * RL + (t & 15);   // 16 consecutive cells
    const int cc = t >> 4;                         // lane-in-cell 0..15
    float s = 0.f;
    for (int k = 0; k < NBLK_A / RL; ++k)          // 36 chained loads
        s += Tp[(size_t)(cc + RL * k) * CELLS + cell];
    red[t] = s;
    __syncthreads();
    if (t < RL) {                                  // fold 16 lane-partials
        float acc = 0.f;
#pragma unroll
        for (int g = 0; g < RL; ++g) acc += red[t + RL * g];
        T[blockIdx.x * RL + t] = acc;
    }
}

// ---- Phase B: scores -> softmax_d -> partial S; no atomics ----
__global__ __launch_bounds__(256) void caps_S(
    const float* __restrict__ u, const float* __restrict__ W,
    const float* __restrict__ Bp, const float* __restrict__ T,
    float* __restrict__ Sp)
{
    const int t = threadIdx.x, j = t & 15, b = t >> 4;
    constexpr float RS8 = 0.35355339059327373f;  // 1/sqrt(8)

    float Treg[ND];                               // T[.,b,j] (L2-hot 10 KB)
#pragma unroll
    for (int q = 0; q < ND; ++q) Treg[q] = T[q * 256 + t];

    float Sacc[ND];
#pragma unroll
    for (int q = 0; q < ND; ++q) Sacc[q] = 0.f;

    const int n0 = blockIdx.x * NCHB;
    for (int nn = 0; nn < NCHB; ++nn) {
        const int n = n0 + nn;
        float uf[DP];
        load8(u + ((size_t)b * NN + n) * DP, uf);

        float uh[ND], a[ND];
#pragma unroll
        for (int q = 0; q < ND; ++q) {            // 10 independent load8s
            float wf[DP];
            load8(W + (((size_t)q * NN + n) * DD + j) * DP, wf);
            float s = 0.f;
#pragma unroll
            for (int i = 0; i < DP; ++i) s += wf[i] * uf[i];
            uh[q] = s;
            float v = Treg[q] * s;                // butterfly over 16 j-lanes
            v += __shfl_xor(v, 8, 16);
            v += __shfl_xor(v, 4, 16);
            v += __shfl_xor(v, 2, 16);
            v += __shfl_xor(v, 1, 16);
            a[q] = v * RS8;
        }
        float m = a[0];
#pragma unroll
        for (int q = 1; q < ND; ++q) m = fmaxf(m, a[q]);
        float e[ND], se = 0.f;
#pragma unroll
        for (int q = 0; q < ND; ++q) { e[q] = expf(a[q] - m); se += e[q]; }
        const float inv_se = 1.f / se;
#pragma unroll
        for (int q = 0; q < ND; ++q)
            Sacc[q] += (Bp[q * NN + n] + e[q] * inv_se) * uh[q];
    }
    float* dst = Sp + (size_t)blockIdx.x * CELLS;
#pragma unroll
    for (int q = 0; q < ND; ++q) dst[q * 256 + t] = Sacc[q];
}

// ---- reduce Sp[576][2560] + fused squash: 160 blocks = (q,b) ----
__global__ __launch_bounds__(256) void reduce_S_out(
    const float* __restrict__ Sp, float* __restrict__ out)
{
    __shared__ float red[256];
    const int q = blockIdx.x >> 4, b = blockIdx.x & 15;
    const int t = threadIdx.x, j = t & 15, cc = t >> 4;
    const int cell = q * 256 + b * 16 + j;
    float s = 0.f;
    for (int k = 0; k < NBLK_B / RL; ++k)          // 36 chained loads
        s += Sp[(size_t)(cc + RL * k) * CELLS + cell];
    red[t] = s;
    __syncthreads();
    if (t < RL) {                                  // t = j here
        float Sv = 0.f;
#pragma unroll
        for (int g = 0; g < RL; ++g) Sv += red[t + RL * g];
        float n2 = Sv * Sv;                        // lanes 0..15: width-16 fly
#pragma unroll
        for (int off = 8; off >= 1; off >>= 1) n2 += __shfl_xor(n2, off, 16);
        const float nrm = sqrtf(n2);
        const float coef = 1.f - 1.f / (expf(nrm) + 1e-7f);
        out[((size_t)b * ND + q) * DD + t] = Sv * (coef / (nrm + 1e-7f));
    }
}

extern "C" void kernel_launch(void* const* d_in, const int* in_sizes, int n_in,
                              void* d_out, int out_size, void* d_ws, size_t ws_size,
                              hipStream_t stream) {
    const float* u  = nullptr;   // 147456
    const float* W  = nullptr;   // 1474560
    const float* Bp = nullptr;   // 11520
    for (int i = 0; i < n_in; ++i) {
        const int s = in_sizes[i];
        if (s == BN * NN * DP)            u  = (const float*)d_in[i];
        else if (s == ND * NN * DD * DP)  W  = (const float*)d_in[i];
        else if (s == ND * NN)            Bp = (const float*)d_in[i];
    }
    float* out = (float*)d_out;
    float* Tp = (float*)d_ws;                     // 576*2560 fp32 = 5.9 MB
    float* T  = Tp + (size_t)NBLK_A * CELLS;      // 2560 fp32
    float* Sp = T + CELLS;                        // 576*2560 fp32 = 5.9 MB

    caps_T      <<<dim3(NBLK_A), 256, 0, stream>>>(u, W, Tp);
    reduce_T    <<<dim3(CELLS / RL), 256, 0, stream>>>(Tp, T);
    caps_S      <<<dim3(NBLK_B), 256, 0, stream>>>(u, W, Bp, T, Sp);
    reduce_S_out<<<dim3(ND * BN), 256, 0, stream>>>(Sp, out);
}